// Round 14
// baseline (169.920 us; speedup 1.0000x reference)
//
#include <hip/hip_runtime.h>
#include <hip/hip_cooperative_groups.h>

namespace cg = cooperative_groups;

typedef __attribute__((ext_vector_type(4))) float f32x4;
typedef __attribute__((ext_vector_type(8))) __bf16 bf16x8;

__device__ __forceinline__ unsigned short f2bf(float f) {
  unsigned int u = __float_as_uint(f);
  u += 0x7FFFu + ((u >> 16) & 1u);
  return (unsigned short)(u >> 16);
}
__device__ __forceinline__ float bf2f(unsigned short u) {
  return __uint_as_float(((unsigned int)u) << 16);
}
__device__ __forceinline__ float ex2(float x) {
  return __builtin_amdgcn_exp2f(x);   // native v_exp_f32 (base-2)
}

__device__ __forceinline__ void gload16(const void* g, void* l) {
  __builtin_amdgcn_global_load_lds(
      (const __attribute__((address_space(1))) void*)g,
      (__attribute__((address_space(3))) void*)l, 16, 0, 0);
}

#define QSCALE 0.09016844005555897f  /* (1/16) * log2(e) */

// ---------------- weight fp32 -> bf16 ----------------
__global__ __launch_bounds__(256)
void prep_weights(const float* __restrict__ wq, const float* __restrict__ wk,
                  const float* __restrict__ wv, const float* __restrict__ wo,
                  unsigned short* __restrict__ out) {
  int i = blockIdx.x * 256 + threadIdx.x;  // 4 * 65536 total
  const float* src = (i < 65536) ? wq : (i < 131072) ? wk : (i < 196608) ? wv : wo;
  out[i] = f2bf(src[i & 65535]);
}

// ---------------- GroupNorm, cooperative single-x-read version ----------------
// Grid 256 x 512 (1 block/CU). Block = (b*32+g)*2 + h; owns n in [h*2048,+2048).
// x values held in registers across stats->apply; grid.sync() joins the two
// half-blocks' partial sums. Single read of x, full-GPU BW.
__global__ __launch_bounds__(512)
void groupnorm_coop(const float* __restrict__ x, const float* __restrict__ gamma,
                    const float* __restrict__ beta, unsigned short* __restrict__ hnT,
                    float2* __restrict__ part) {
  const int blk = blockIdx.x;
  const int h = blk & 1, bg = blk >> 1;
  const int b = bg >> 5, g = bg & 31;
  const int tid = threadIdx.x;
  const float* xb = x + ((size_t)b * 256 + (size_t)g * 8) * 4096 + h * 2048;

  float v[8][4];
  float s = 0.f, ss = 0.f;
  #pragma unroll
  for (int c = 0; c < 8; ++c)
    #pragma unroll
    for (int s2 = 0; s2 < 4; ++s2) {
      float val = xb[c * 4096 + s2 * 512 + tid];
      v[c][s2] = val; s += val; ss += val * val;
    }
  __shared__ float rs[8], rss[8];
  for (int m = 1; m <= 32; m <<= 1) { s += __shfl_xor(s, m); ss += __shfl_xor(ss, m); }
  const int lane = tid & 63, wid = tid >> 6;
  if (lane == 0) { rs[wid] = s; rss[wid] = ss; }
  __syncthreads();
  if (tid == 0) {
    float a = 0.f, b2 = 0.f;
    #pragma unroll
    for (int i = 0; i < 8; ++i) { a += rs[i]; b2 += rss[i]; }
    part[blk] = make_float2(a, b2);
  }
  cg::this_grid().sync();
  const int base = blk & ~1;
  const float2 p0 = part[base], p1 = part[base + 1];
  const float mean = (p0.x + p1.x) * (1.f / 32768.f);
  const float var  = (p0.y + p1.y) * (1.f / 32768.f) - mean * mean;
  const float rstd = rsqrtf(var + 1e-6f);

  float gk[8], bk2[8];
  #pragma unroll
  for (int c = 0; c < 8; ++c) {
    float ga = gamma[g * 8 + c] * rstd;
    gk[c]  = ga;
    bk2[c] = beta[g * 8 + c] - mean * ga;
  }
  unsigned short* outp = hnT + (size_t)b * 4096 * 256 + g * 8;
  #pragma unroll
  for (int s2 = 0; s2 < 4; ++s2) {
    const int n = h * 2048 + s2 * 512 + tid;
    union { unsigned short u[8]; uint4 q; } pk;
    #pragma unroll
    for (int c = 0; c < 8; ++c) pk.u[c] = f2bf(v[c][s2] * gk[c] + bk2[c]);
    *reinterpret_cast<uint4*>(outp + (size_t)n * 256) = pk.q;
  }
}

// ---------------- GroupNorm fallback (r13 kernel) ----------------
__global__ __launch_bounds__(1024)
void groupnorm_kernel(const float* __restrict__ x, const float* __restrict__ gamma,
                      const float* __restrict__ beta, unsigned short* __restrict__ hnT) {
  const int blk = blockIdx.x;        // b*32 + g
  const int b = blk >> 5, g = blk & 31;
  const int N = 4096;
  const float* xb = x + ((size_t)b * 256 + (size_t)g * 8) * N;
  const int tid = threadIdx.x;

  float s = 0.f, ss = 0.f;
  for (int c = 0; c < 8; ++c) {
    const float* xc = xb + (size_t)c * N;
    for (int i = tid; i < N; i += 1024) { float v = xc[i]; s += v; ss += v * v; }
  }
  __shared__ float rs[16], rss[16];
  for (int m = 1; m <= 32; m <<= 1) { s += __shfl_xor(s, m); ss += __shfl_xor(ss, m); }
  const int lane = tid & 63, wid = tid >> 6;
  if (lane == 0) { rs[wid] = s; rss[wid] = ss; }
  __syncthreads();
  s = 0.f; ss = 0.f;
  #pragma unroll
  for (int i = 0; i < 16; ++i) { s += rs[i]; ss += rss[i]; }
  const float mean = s * (1.f / 32768.f);
  const float var  = ss * (1.f / 32768.f) - mean * mean;
  const float rstd = rsqrtf(var + 1e-6f);

  float gk[8], bk2[8];
  #pragma unroll
  for (int c = 0; c < 8; ++c) {
    float ga = gamma[g * 8 + c] * rstd;
    gk[c]  = ga;
    bk2[c] = beta[g * 8 + c] - mean * ga;
  }
  unsigned short* outp = hnT + (size_t)b * 256 * N + g * 8;
  for (int i = tid; i < N; i += 1024) {
    union { unsigned short u[8]; uint4 v; } pk;
    #pragma unroll
    for (int c = 0; c < 8; ++c) pk.u[c] = f2bf(xb[(size_t)c * N + i] * gk[c] + bk2[c]);
    *reinterpret_cast<uint4*>(outp + (size_t)i * 256) = pk.v;
  }
}

// ---------------- fused QKV projection ----------------
__global__ __launch_bounds__(256, 2)
void qkv_fused(const unsigned short* __restrict__ WB,
               const unsigned short* __restrict__ hnT,
               const float* __restrict__ bq, const float* __restrict__ bk,
               const float* __restrict__ bv,
               unsigned short* __restrict__ Qt, unsigned short* __restrict__ Kt,
               unsigned short* __restrict__ Vp) {
  __shared__ alignas(1024) unsigned char lds[32768];  // B 16KB @0, A dbuf 2x8KB @16384
  const int tid = threadIdx.x, lane = tid & 63, w = tid >> 6;
  const int hig = lane >> 4, l15 = lane & 15;
  const int z = blockIdx.y, nt = blockIdx.x;
  const int n0 = nt * 32;
  const size_t zoff = (size_t)z * 1048576;
  const unsigned short* hnB = hnT + zoff + (size_t)n0 * 256;

  // stage B tile (32 rows x 512B): 4 passes x 256 lanes x 16B
  #pragma unroll
  for (int p = 0; p < 4; ++p) {
    const int idx = p * 256 + tid;
    const int r = idx >> 5, sl = idx & 31;
    gload16(hnB + (size_t)r * 256 + ((sl ^ (r & 7)) << 3), lds + idx * 16);
  }

  const int qs = (lane & 3) ^ ((lane >> 3) & 3);
  const int ar = tid >> 2, asq = tid & 3;
  auto stageA = [&](int d, int s) {
    const unsigned short* base = WB + (s >> 3) * 32768 + (s & 7) * 32 + qs * 8;
    unsigned char* dst = lds + 16384 + d * 8192;
    gload16(base + (size_t)ar * 256,        dst + ar * 64 + asq * 16);
    gload16(base + (size_t)(ar + 64) * 256, dst + (ar + 64) * 64 + asq * 16);
  };

  const int aslot = hig ^ ((l15 >> 1) & 3);
  f32x4 acc[2][2] = {};

  stageA(0, 0);
  __syncthreads();  // drains B + A(0)

  for (int s = 0; s < 48; ++s) {
    const int d = s & 1;
    if (s + 1 < 48) stageA(d ^ 1, s + 1);
    const int kt = s & 7;
    bf16x8 af[2];
    #pragma unroll
    for (int mf = 0; mf < 2; ++mf)
      af[mf] = *reinterpret_cast<const bf16x8*>(
          lds + 16384 + d * 8192 + (w * 32 + mf * 16 + l15) * 64 + aslot * 16);
    #pragma unroll
    for (int nf = 0; nf < 2; ++nf) {
      const int rb = nf * 16 + l15;
      bf16x8 bfr = *reinterpret_cast<const bf16x8*>(
          lds + rb * 512 + (((kt * 4 + hig) ^ (rb & 7)) << 4));
      acc[0][nf] = __builtin_amdgcn_mfma_f32_16x16x32_bf16(af[0], bfr, acc[0][nf], 0, 0, 0);
      acc[1][nf] = __builtin_amdgcn_mfma_f32_16x16x32_bf16(af[1], bfr, acc[1][nf], 0, 0, 0);
    }
    if (kt == 7) {  // epilogue for tile sel
      const int sel = s >> 3, wsel = sel >> 1, mh = sel & 1;
      #pragma unroll
      for (int mf = 0; mf < 2; ++mf) {
        const int gm0 = mh * 128 + w * 32 + mf * 16 + 4 * hig;
        #pragma unroll
        for (int nf = 0; nf < 2; ++nf) {
          const int n = n0 + nf * 16 + l15;
          if (wsel == 0) {
            ushort4 pk;
            pk.x = f2bf((acc[mf][nf][0] + bq[gm0])     * QSCALE);
            pk.y = f2bf((acc[mf][nf][1] + bq[gm0 + 1]) * QSCALE);
            pk.z = f2bf((acc[mf][nf][2] + bq[gm0 + 2]) * QSCALE);
            pk.w = f2bf((acc[mf][nf][3] + bq[gm0 + 3]) * QSCALE);
            *reinterpret_cast<ushort4*>(Qt + zoff + (size_t)n * 256 + gm0) = pk;
          } else if (wsel == 1) {
            ushort4 pk;
            pk.x = f2bf(acc[mf][nf][0] + bk[gm0]);
            pk.y = f2bf(acc[mf][nf][1] + bk[gm0 + 1]);
            pk.z = f2bf(acc[mf][nf][2] + bk[gm0 + 2]);
            pk.w = f2bf(acc[mf][nf][3] + bk[gm0 + 3]);
            *reinterpret_cast<ushort4*>(Kt + zoff + (size_t)n * 256 + gm0) = pk;
          } else {
            #pragma unroll
            for (int e = 0; e < 4; ++e)
              Vp[zoff + (size_t)(gm0 + e) * 4096 + n] = f2bf(acc[mf][nf][e] + bv[gm0 + e]);
          }
          acc[mf][nf] = f32x4{0.f, 0.f, 0.f, 0.f};
        }
      }
    }
    __syncthreads();
  }
}

// ---------------- fused flash attention (r13) ----------------
__global__ __launch_bounds__(256, 2)
void flash_attn(const unsigned short* __restrict__ Qt,
                const unsigned short* __restrict__ Kt,
                const unsigned short* __restrict__ Vp,
                unsigned short* __restrict__ Opart, float* __restrict__ lpart) {
  __shared__ alignas(1024) unsigned char lds[81920];
  const int tid = threadIdx.x, lane = tid & 63, w = tid >> 6;
  const int hig = lane >> 4, l15 = lane & 15;
  // XCD-aware bijective decode (hardware XCD = blockIdx % 8)
  const int bid = blockIdx.x;
  const int xcd = bid & 7, k = bid >> 3;
  const int combo = xcd * 2 + (k >> 5);       // 0..15
  const int jh = combo & 3, z = combo >> 2, qtb = k & 31;
  const size_t zoff = (size_t)z * 1048576;
  const unsigned short* Qz = Qt + zoff;
  const unsigned short* Kz = Kt + zoff;
  const unsigned short* Vz = Vp + zoff;
  const int q0 = qtb * 128 + w * 32;
  const int jb0 = jh * 1024;

  bf16x8 qfr[2][8];
  #pragma unroll
  for (int qf = 0; qf < 2; ++qf)
    #pragma unroll
    for (int ks = 0; ks < 8; ++ks)
      qfr[qf][ks] = *reinterpret_cast<const bf16x8*>(
          Qz + (size_t)(q0 + qf * 16 + l15) * 256 + ks * 32 + hig * 8);

  unsigned char* Pw = lds + 65536 + w * 4096;

  const unsigned short* pK[4];
  const unsigned short* pV[4];
  #pragma unroll
  for (int g = 0; g < 4; ++g) {
    const int jr = w * 8 + g * 2 + (lane >> 5);
    pK[g] = Kz + (size_t)(jb0 + jr) * 256 + (((lane & 31) ^ (jr & 7)) << 3);
    // V: row-pair r=c>>1 (128B), raw slot = 4(c&1)+(j>>3), stored ^ (r&7).
    const int rloc = lane >> 3;
    const int sraw = (lane & 7) ^ rloc;
    const int cV = 2 * (w * 32 + g * 8 + rloc) + (sraw >> 2);
    pV[g] = Vz + (size_t)cV * 4096 + jb0 + (sraw & 3) * 8;
  }

  auto stage = [&](int d, int t) {
    unsigned char* Kd = lds + d * 16384 + w * 4096;
    unsigned char* Vd = lds + 32768 + d * 16384 + w * 4096;
    #pragma unroll
    for (int g = 0; g < 4; ++g) gload16(pK[g] + (size_t)t * 8192, Kd + g * 1024);
    #pragma unroll
    for (int g = 0; g < 4; ++g) gload16(pV[g] + (size_t)t * 32, Vd + g * 1024);
  };

  f32x4 o0[16] = {}, o1[16] = {};
  float l0 = 0.f, l1 = 0.f;   // per-lane partials; cross-lane reduce at epilogue

  stage(0, 0);
  for (int t = 0; t < 32; ++t) {
    asm volatile("s_waitcnt vmcnt(0)" ::: "memory");
    __builtin_amdgcn_s_barrier();
    __builtin_amdgcn_sched_barrier(0);
    const int cur = t & 1;
    if (t + 1 < 32) stage(cur ^ 1, t + 1);

    const unsigned char* Kb = lds + cur * 16384;
    const unsigned char* Vb = lds + 32768 + cur * 16384;

    // ---- QK^T (swapped): sA[jf][qh] rows j=16jf+4hig+e, col q=l15 ----
    f32x4 sA[2][2] = {};
    __builtin_amdgcn_s_setprio(1);
    #pragma unroll
    for (int ks = 0; ks < 8; ++ks) {
      #pragma unroll
      for (int jf = 0; jf < 2; ++jf) {
        const int jl = jf * 16 + l15;
        bf16x8 kf = *reinterpret_cast<const bf16x8*>(
            Kb + jl * 512 + (((4 * ks + hig) ^ (jl & 7)) << 4));
        sA[jf][0] = __builtin_amdgcn_mfma_f32_16x16x32_bf16(kf, qfr[0][ks], sA[jf][0], 0, 0, 0);
        sA[jf][1] = __builtin_amdgcn_mfma_f32_16x16x32_bf16(kf, qfr[1][ks], sA[jf][1], 0, 0, 0);
      }
    }
    __builtin_amdgcn_s_setprio(0);

    // ---- static-max softmax: P = 2^s (scores O(1) by construction) ----
    #pragma unroll
    for (int jf = 0; jf < 2; ++jf) {
      const int so = (((2 * jf + (hig >> 1)) ^ (l15 & 7)) << 4) + ((hig & 1) << 3);
      {
        float p0 = ex2(sA[jf][0][0]), p1 = ex2(sA[jf][0][1]);
        float p2 = ex2(sA[jf][0][2]), p3 = ex2(sA[jf][0][3]);
        l0 += (p0 + p1) + (p2 + p3);
        union { __bf16 b[4]; uint2 u; } pk;
        pk.b[0] = (__bf16)p0; pk.b[1] = (__bf16)p1;
        pk.b[2] = (__bf16)p2; pk.b[3] = (__bf16)p3;
        *reinterpret_cast<uint2*>(Pw + l15 * 128 + so) = pk.u;
      }
      {
        float p0 = ex2(sA[jf][1][0]), p1 = ex2(sA[jf][1][1]);
        float p2 = ex2(sA[jf][1][2]), p3 = ex2(sA[jf][1][3]);
        l1 += (p0 + p1) + (p2 + p3);
        union { __bf16 b[4]; uint2 u; } pk;
        pk.b[0] = (__bf16)p0; pk.b[1] = (__bf16)p1;
        pk.b[2] = (__bf16)p2; pk.b[3] = (__bf16)p3;
        *reinterpret_cast<uint2*>(Pw + (16 + l15) * 128 + so) = pk.u;
      }
    }

    // ---- PV: A = P rows i, B = V cols c, k = 32 j ----
    const int pso = (hig ^ (l15 & 7)) << 4;
    bf16x8 pa0 = *reinterpret_cast<const bf16x8*>(Pw + l15 * 128 + pso);
    bf16x8 pa1 = *reinterpret_cast<const bf16x8*>(Pw + (16 + l15) * 128 + pso);
    const int vslot = ((l15 & 1) * 4 + hig) ^ (l15 >> 1);
    __builtin_amdgcn_s_setprio(1);
    #pragma unroll
    for (int nf = 0; nf < 16; ++nf) {
      bf16x8 vb = *reinterpret_cast<const bf16x8*>(
          Vb + (8 * nf + (l15 >> 1)) * 128 + (vslot << 4));
      o0[nf] = __builtin_amdgcn_mfma_f32_16x16x32_bf16(pa0, vb, o0[nf], 0, 0, 0);
      o1[nf] = __builtin_amdgcn_mfma_f32_16x16x32_bf16(pa1, vb, o1[nf], 0, 0, 0);
    }
    __builtin_amdgcn_s_setprio(0);
  }

  // deferred cross-lane l reduction (hig-groups hold disjoint j partials)
  l0 += __shfl_xor(l0, 16); l0 += __shfl_xor(l0, 32);
  l1 += __shfl_xor(l1, 16); l1 += __shfl_xor(l1, 32);

  // epilogue: un-normalized partials (bf16) + l for the merge kernel
  unsigned short* Ob = Opart + ((size_t)(jh * 4 + z) * 4096 + q0) * 256;
  #pragma unroll
  for (int qf = 0; qf < 2; ++qf)
    #pragma unroll
    for (int nf = 0; nf < 16; ++nf)
      #pragma unroll
      for (int e = 0; e < 4; ++e) {
        const int row = qf * 16 + 4 * hig + e;
        Ob[(size_t)row * 256 + nf * 16 + l15] = f2bf((qf == 0) ? o0[nf][e] : o1[nf][e]);
      }
  if (hig == 0) {
    const size_t mb = (size_t)(jh * 4 + z) * 4096 + q0;
    lpart[mb + l15] = l0;  lpart[mb + 16 + l15] = l1;
  }
}

// ---------------- merge the four j-quarters (plain sum) -> Ht bf16 ----------------
__global__ __launch_bounds__(256)
void flash_merge(const unsigned short* __restrict__ Opart,
                 const float* __restrict__ lpart, unsigned short* __restrict__ Ht) {
  const int t = threadIdx.x;
  const int r = blockIdx.x * 4 + (t >> 6);   // r = z*4096 + n, in [0,16384)
  const int c = (t & 63) * 4;
  const int z = r >> 12, n = r & 4095;
  float lsum = 0.f;
  #pragma unroll
  for (int h = 0; h < 4; ++h) lsum += lpart[(h * 4 + z) * 4096 + n];
  const float inv = 1.f / lsum;
  float acc[4] = {};
  #pragma unroll
  for (int h = 0; h < 4; ++h) {
    ushort4 v = *reinterpret_cast<const ushort4*>(
        Opart + ((size_t)((h * 4 + z) * 4096 + n)) * 256 + c);
    acc[0] += bf2f(v.x); acc[1] += bf2f(v.y);
    acc[2] += bf2f(v.z); acc[3] += bf2f(v.w);
  }
  ushort4 pk;
  pk.x = f2bf(acc[0] * inv); pk.y = f2bf(acc[1] * inv);
  pk.z = f2bf(acc[2] * inv); pk.w = f2bf(acc[3] * inv);
  *reinterpret_cast<ushort4*>(Ht + (size_t)r * 256 + c) = pk;
}

// ---------------- 128x128 MFMA GEMM (O-projection w/ residual) ----------------
__global__ __launch_bounds__(256)
void gemm_out(const unsigned short* __restrict__ A,
              const unsigned short* __restrict__ B, long bStrideZ,
              float* __restrict__ Out, long oStrideZ,
              const float* __restrict__ bias,
              const float* __restrict__ resid, long rStrideZ,
              int M, int N, int K) {
  __shared__ alignas(1024) unsigned char lds[32768];
  const int tid  = threadIdx.x;
  const int lane = tid & 63;
  const int hi   = lane >> 4;
  const int l15  = lane & 15;
  const int wid  = tid >> 6;
  const int wm = wid >> 1, wn = wid & 1;
  const int z  = blockIdx.z;
  const int m0 = blockIdx.y * 128;
  const int n0 = blockIdx.x * 128;
  const unsigned short* Az = A;
  const unsigned short* Bz = B + (size_t)z * bStrideZ;

  const int c0 = wid * 2, c1 = wid * 2 + 1;
  const int rr = lane >> 2;
  const int qs = (lane & 3) ^ ((lane >> 3) & 3);
  const unsigned short* pa0 = Az + (size_t)(m0 + c0 * 16 + rr) * K + qs * 8;
  const unsigned short* pa1 = Az + (size_t)(m0 + c1 * 16 + rr) * K + qs * 8;
  const unsigned short* pb0 = Bz + (size_t)(n0 + c0 * 16 + rr) * K + qs * 8;
  const unsigned short* pb1 = Bz + (size_t)(n0 + c1 * 16 + rr) * K + qs * 8;
  unsigned char* lA0 = lds + c0 * 1024;
  unsigned char* lA1 = lds + c1 * 1024;
  unsigned char* lB0 = lds + 8192 + c0 * 1024;
  unsigned char* lB1 = lds + 8192 + c1 * 1024;

  const int slot = hi ^ ((l15 >> 1) & 3);
  int roffA[4], roffB[4];
  #pragma unroll
  for (int t = 0; t < 4; ++t) {
    roffA[t] = (wm * 64 + t * 16 + l15) * 64 + slot * 16;
    roffB[t] = 8192 + (wn * 64 + t * 16 + l15) * 64 + slot * 16;
  }

  f32x4 acc[4][4] = {};

  const int nk = K >> 5;
  gload16(pa0, lA0); gload16(pa1, lA1);
  gload16(pb0, lB0); gload16(pb1, lB1);
  __syncthreads();

  int cur = 0;
  for (int kt = 0; kt < nk; ++kt) {
    if (kt + 1 < nk) {
      const size_t ko = (size_t)(kt + 1) * 32;
      const int bo = (cur ^ 1) * 16384;
      gload16(pa0 + ko, lA0 + bo); gload16(pa1 + ko, lA1 + bo);
      gload16(pb0 + ko, lB0 + bo); gload16(pb1 + ko, lB1 + bo);
    }
    const unsigned char* base = lds + cur * 16384;
    bf16x8 af[4], bfr[4];
    #pragma unroll
    for (int t = 0; t < 4; ++t) {
      af[t]  = *reinterpret_cast<const bf16x8*>(base + roffA[t]);
      bfr[t] = *reinterpret_cast<const bf16x8*>(base + roffB[t]);
    }
    #pragma unroll
    for (int mt = 0; mt < 4; ++mt)
      #pragma unroll
      for (int nt = 0; nt < 4; ++nt)
        acc[mt][nt] = __builtin_amdgcn_mfma_f32_16x16x32_bf16(af[mt], bfr[nt], acc[mt][nt], 0, 0, 0);
    __syncthreads();
    cur ^= 1;
  }

  const int gmb = m0 + wm * 64;
  const int gnb = n0 + wn * 64;
  float* O = Out + (size_t)z * oStrideZ;
  const float* R = resid + (size_t)z * rStrideZ;
  #pragma unroll
  for (int mt = 0; mt < 4; ++mt) {
    const int gm0 = gmb + mt * 16 + 4 * hi;
    #pragma unroll
    for (int nt = 0; nt < 4; ++nt) {
      const int gn = gnb + nt * 16 + l15;
      #pragma unroll
      for (int e = 0; e < 4; ++e) {
        size_t idx = (size_t)(gm0 + e) * N + gn;
        O[idx] = acc[mt][nt][e] + bias[gm0 + e] + R[idx];
      }
    }
  }
}

__global__ void ws_too_small(float* out, float v) {
  if (threadIdx.x == 0 && blockIdx.x == 0) out[0] = v;
}

extern "C" void kernel_launch(void* const* d_in, const int* in_sizes, int n_in,
                              void* d_out, int out_size, void* d_ws, size_t ws_size,
                              hipStream_t stream) {
  const float* x     = (const float*)d_in[0];
  const float* gamma = (const float*)d_in[1];
  const float* beta  = (const float*)d_in[2];
  const float* Wq    = (const float*)d_in[3];
  const float* bq    = (const float*)d_in[4];
  const float* Wk    = (const float*)d_in[5];
  const float* bk    = (const float*)d_in[6];
  const float* Wv    = (const float*)d_in[7];
  const float* bv    = (const float*)d_in[8];
  const float* Wo    = (const float*)d_in[9];
  const float* bo    = (const float*)d_in[10];
  float* out = (float*)d_out;

  unsigned char* ws = (unsigned char*)d_ws;
  unsigned short* WB    = (unsigned short*)(ws);             // [4][256][256] bf16 (q,k,v,o)
  unsigned short* hnT   = (unsigned short*)(ws + 524288);    // [4][4096][256]
  float*          lpart = (float*)(ws + 524288);             // [4][4][4096] (reuses hnT after projections)
  unsigned short* Qt    = (unsigned short*)(ws + 8912896);   // [4][4096][256]
  unsigned short* Kt    = (unsigned short*)(ws + 17301504);  // [4][4096][256]
  unsigned short* V     = (unsigned short*)(ws + 25690112);  // [4][256][4096]
  unsigned short* Ht    = (unsigned short*)(ws + 34078720);  // [4][4096][256]
  unsigned short* Opart = (unsigned short*)(ws + 42467328);  // [16][4096][256] bf16
  float2*         gnpart = (float2*)(ws + 76021760);         // [256] float2 (free tail)

  if (ws_size < 76283904) {
    hipMemsetAsync(d_out, 0, (size_t)out_size * 4, stream);
    ws_too_small<<<1, 64, 0, stream>>>(out, (float)ws_size);
    return;
  }

  prep_weights<<<1024, 256, 0, stream>>>(Wq, Wk, Wv, Wo, WB);

  // GroupNorm: cooperative single-x-read version; fall back to r13 kernel if
  // cooperative launch is unavailable (identical output either way).
  {
    void* gnargs[] = {(void*)&x, (void*)&gamma, (void*)&beta, (void*)&hnT, (void*)&gnpart};
    hipError_t ce = hipLaunchCooperativeKernel((const void*)groupnorm_coop,
                                               dim3(256), dim3(512), gnargs, 0, stream);
    if (ce != hipSuccess) {
      groupnorm_kernel<<<128, 1024, 0, stream>>>(x, gamma, beta, hnT);
    }
  }

  // fused QKV projections (Q pre-scaled by 1/16*log2e)
  qkv_fused<<<dim3(128, 4), 256, 0, stream>>>(WB, hnT, bq, bk, bv, Qt, Kt, V);

  // fused attention (static-max base-2 softmax), j split 4-way, XCD-swizzled
  flash_attn<<<512, 256, 0, stream>>>(Qt, Kt, V, Opart, lpart);
  flash_merge<<<4096, 256, 0, stream>>>(Opart, lpart, Ht);

  // out[co][n] = sum_c Wo[co][c] * Ht[n][c] + bo[co] + x
  gemm_out<<<dim3(32, 2, 4), 256, 0, stream>>>(
      WB + 196608, Ht, 1048576, out, 1048576, bo, x, 1048576, 256, 4096, 256);
}

// Round 15
// 137.066 us; speedup vs baseline: 1.2397x; 1.2397x over previous
//
#include <hip/hip_runtime.h>

typedef __attribute__((ext_vector_type(4))) float f32x4;
typedef __attribute__((ext_vector_type(8))) __bf16 bf16x8;

__device__ __forceinline__ unsigned short f2bf(float f) {
  unsigned int u = __float_as_uint(f);
  u += 0x7FFFu + ((u >> 16) & 1u);
  return (unsigned short)(u >> 16);
}
__device__ __forceinline__ float bf2f(unsigned short u) {
  return __uint_as_float(((unsigned int)u) << 16);
}
__device__ __forceinline__ float ex2(float x) {
  return __builtin_amdgcn_exp2f(x);   // native v_exp_f32 (base-2)
}

__device__ __forceinline__ void gload16(const void* g, void* l) {
  __builtin_amdgcn_global_load_lds(
      (const __attribute__((address_space(1))) void*)g,
      (__attribute__((address_space(3))) void*)l, 16, 0, 0);
}

#define QSCALE 0.09016844005555897f  /* (1/16) * log2(e) */

// ---------------- weight fp32 -> bf16 ----------------
__global__ __launch_bounds__(256)
void prep_weights(const float* __restrict__ wq, const float* __restrict__ wk,
                  const float* __restrict__ wv, const float* __restrict__ wo,
                  unsigned short* __restrict__ out) {
  int i = blockIdx.x * 256 + threadIdx.x;  // 4 * 65536 total
  const float* src = (i < 65536) ? wq : (i < 131072) ? wk : (i < 196608) ? wv : wo;
  out[i] = f2bf(src[i & 65535]);
}

// ---------------- GroupNorm, split-stats version (no sync needed) ----------------
// Grid 256 x 512 (full GPU). Block = (b*32+g)*2 + h; owns n in [h*2048,+2048).
// Own half held in registers; other half read ONLY for stats (redundant compute
// replaces the grid sync). Same total HBM traffic as the 2-pass kernel, 2x the
// parallelism, apply pass from registers.
__global__ __launch_bounds__(512)
void groupnorm_split(const float* __restrict__ x, const float* __restrict__ gamma,
                     const float* __restrict__ beta, unsigned short* __restrict__ hnT) {
  const int blk = blockIdx.x;
  const int h = blk & 1, bg = blk >> 1;
  const int b = bg >> 5, g = bg & 31;
  const int tid = threadIdx.x;
  const float* xg = x + ((size_t)b * 256 + (size_t)g * 8) * 4096;
  const float* xo = xg + h * 2048;          // own half
  const float* xr = xg + (h ^ 1) * 2048;    // other half (stats only)

  float v[8][4];
  float s = 0.f, ss = 0.f;
  #pragma unroll
  for (int c = 0; c < 8; ++c)
    #pragma unroll
    for (int s2 = 0; s2 < 4; ++s2) {
      float val = xo[c * 4096 + s2 * 512 + tid];
      v[c][s2] = val; s += val; ss += val * val;
    }
  #pragma unroll
  for (int c = 0; c < 8; ++c)
    #pragma unroll
    for (int s2 = 0; s2 < 4; ++s2) {
      float val = xr[c * 4096 + s2 * 512 + tid];
      s += val; ss += val * val;
    }
  __shared__ float rs[8], rss[8];
  for (int m = 1; m <= 32; m <<= 1) { s += __shfl_xor(s, m); ss += __shfl_xor(ss, m); }
  const int lane = tid & 63, wid = tid >> 6;
  if (lane == 0) { rs[wid] = s; rss[wid] = ss; }
  __syncthreads();
  s = 0.f; ss = 0.f;
  #pragma unroll
  for (int i = 0; i < 8; ++i) { s += rs[i]; ss += rss[i]; }
  const float mean = s * (1.f / 32768.f);
  const float var  = ss * (1.f / 32768.f) - mean * mean;
  const float rstd = rsqrtf(var + 1e-6f);

  float gk[8], bk2[8];
  #pragma unroll
  for (int c = 0; c < 8; ++c) {
    float ga = gamma[g * 8 + c] * rstd;
    gk[c]  = ga;
    bk2[c] = beta[g * 8 + c] - mean * ga;
  }
  unsigned short* outp = hnT + (size_t)b * 4096 * 256 + g * 8;
  #pragma unroll
  for (int s2 = 0; s2 < 4; ++s2) {
    const int n = h * 2048 + s2 * 512 + tid;
    union { unsigned short u[8]; uint4 q; } pk;
    #pragma unroll
    for (int c = 0; c < 8; ++c) pk.u[c] = f2bf(v[c][s2] * gk[c] + bk2[c]);
    *reinterpret_cast<uint4*>(outp + (size_t)n * 256) = pk.q;
  }
}

// ---------------- fused QKV projection ----------------
__global__ __launch_bounds__(256, 2)
void qkv_fused(const unsigned short* __restrict__ WB,
               const unsigned short* __restrict__ hnT,
               const float* __restrict__ bq, const float* __restrict__ bk,
               const float* __restrict__ bv,
               unsigned short* __restrict__ Qt, unsigned short* __restrict__ Kt,
               unsigned short* __restrict__ Vp) {
  __shared__ alignas(1024) unsigned char lds[32768];  // B 16KB @0, A dbuf 2x8KB @16384
  const int tid = threadIdx.x, lane = tid & 63, w = tid >> 6;
  const int hig = lane >> 4, l15 = lane & 15;
  const int z = blockIdx.y, nt = blockIdx.x;
  const int n0 = nt * 32;
  const size_t zoff = (size_t)z * 1048576;
  const unsigned short* hnB = hnT + zoff + (size_t)n0 * 256;

  // stage B tile (32 rows x 512B): 4 passes x 256 lanes x 16B
  #pragma unroll
  for (int p = 0; p < 4; ++p) {
    const int idx = p * 256 + tid;
    const int r = idx >> 5, sl = idx & 31;
    gload16(hnB + (size_t)r * 256 + ((sl ^ (r & 7)) << 3), lds + idx * 16);
  }

  const int qs = (lane & 3) ^ ((lane >> 3) & 3);
  const int ar = tid >> 2, asq = tid & 3;
  auto stageA = [&](int d, int s) {
    const unsigned short* base = WB + (s >> 3) * 32768 + (s & 7) * 32 + qs * 8;
    unsigned char* dst = lds + 16384 + d * 8192;
    gload16(base + (size_t)ar * 256,        dst + ar * 64 + asq * 16);
    gload16(base + (size_t)(ar + 64) * 256, dst + (ar + 64) * 64 + asq * 16);
  };

  const int aslot = hig ^ ((l15 >> 1) & 3);
  f32x4 acc[2][2] = {};

  stageA(0, 0);
  __syncthreads();  // drains B + A(0)

  for (int s = 0; s < 48; ++s) {
    const int d = s & 1;
    if (s + 1 < 48) stageA(d ^ 1, s + 1);
    const int kt = s & 7;
    bf16x8 af[2];
    #pragma unroll
    for (int mf = 0; mf < 2; ++mf)
      af[mf] = *reinterpret_cast<const bf16x8*>(
          lds + 16384 + d * 8192 + (w * 32 + mf * 16 + l15) * 64 + aslot * 16);
    #pragma unroll
    for (int nf = 0; nf < 2; ++nf) {
      const int rb = nf * 16 + l15;
      bf16x8 bfr = *reinterpret_cast<const bf16x8*>(
          lds + rb * 512 + (((kt * 4 + hig) ^ (rb & 7)) << 4));
      acc[0][nf] = __builtin_amdgcn_mfma_f32_16x16x32_bf16(af[0], bfr, acc[0][nf], 0, 0, 0);
      acc[1][nf] = __builtin_amdgcn_mfma_f32_16x16x32_bf16(af[1], bfr, acc[1][nf], 0, 0, 0);
    }
    if (kt == 7) {  // epilogue for tile sel
      const int sel = s >> 3, wsel = sel >> 1, mh = sel & 1;
      #pragma unroll
      for (int mf = 0; mf < 2; ++mf) {
        const int gm0 = mh * 128 + w * 32 + mf * 16 + 4 * hig;
        #pragma unroll
        for (int nf = 0; nf < 2; ++nf) {
          const int n = n0 + nf * 16 + l15;
          if (wsel == 0) {
            ushort4 pk;
            pk.x = f2bf((acc[mf][nf][0] + bq[gm0])     * QSCALE);
            pk.y = f2bf((acc[mf][nf][1] + bq[gm0 + 1]) * QSCALE);
            pk.z = f2bf((acc[mf][nf][2] + bq[gm0 + 2]) * QSCALE);
            pk.w = f2bf((acc[mf][nf][3] + bq[gm0 + 3]) * QSCALE);
            *reinterpret_cast<ushort4*>(Qt + zoff + (size_t)n * 256 + gm0) = pk;
          } else if (wsel == 1) {
            ushort4 pk;
            pk.x = f2bf(acc[mf][nf][0] + bk[gm0]);
            pk.y = f2bf(acc[mf][nf][1] + bk[gm0 + 1]);
            pk.z = f2bf(acc[mf][nf][2] + bk[gm0 + 2]);
            pk.w = f2bf(acc[mf][nf][3] + bk[gm0 + 3]);
            *reinterpret_cast<ushort4*>(Kt + zoff + (size_t)n * 256 + gm0) = pk;
          } else {
            #pragma unroll
            for (int e = 0; e < 4; ++e)
              Vp[zoff + (size_t)(gm0 + e) * 4096 + n] = f2bf(acc[mf][nf][e] + bv[gm0 + e]);
          }
          acc[mf][nf] = f32x4{0.f, 0.f, 0.f, 0.f};
        }
      }
    }
    __syncthreads();
  }
}

// ---------------- fused flash attention (r13, unchanged) ----------------
__global__ __launch_bounds__(256, 2)
void flash_attn(const unsigned short* __restrict__ Qt,
                const unsigned short* __restrict__ Kt,
                const unsigned short* __restrict__ Vp,
                unsigned short* __restrict__ Opart, float* __restrict__ lpart) {
  __shared__ alignas(1024) unsigned char lds[81920];
  const int tid = threadIdx.x, lane = tid & 63, w = tid >> 6;
  const int hig = lane >> 4, l15 = lane & 15;
  // XCD-aware bijective decode (hardware XCD = blockIdx % 8)
  const int bid = blockIdx.x;
  const int xcd = bid & 7, k = bid >> 3;
  const int combo = xcd * 2 + (k >> 5);       // 0..15
  const int jh = combo & 3, z = combo >> 2, qtb = k & 31;
  const size_t zoff = (size_t)z * 1048576;
  const unsigned short* Qz = Qt + zoff;
  const unsigned short* Kz = Kt + zoff;
  const unsigned short* Vz = Vp + zoff;
  const int q0 = qtb * 128 + w * 32;
  const int jb0 = jh * 1024;

  bf16x8 qfr[2][8];
  #pragma unroll
  for (int qf = 0; qf < 2; ++qf)
    #pragma unroll
    for (int ks = 0; ks < 8; ++ks)
      qfr[qf][ks] = *reinterpret_cast<const bf16x8*>(
          Qz + (size_t)(q0 + qf * 16 + l15) * 256 + ks * 32 + hig * 8);

  unsigned char* Pw = lds + 65536 + w * 4096;

  const unsigned short* pK[4];
  const unsigned short* pV[4];
  #pragma unroll
  for (int g = 0; g < 4; ++g) {
    const int jr = w * 8 + g * 2 + (lane >> 5);
    pK[g] = Kz + (size_t)(jb0 + jr) * 256 + (((lane & 31) ^ (jr & 7)) << 3);
    // V: row-pair r=c>>1 (128B), raw slot = 4(c&1)+(j>>3), stored ^ (r&7).
    const int rloc = lane >> 3;
    const int sraw = (lane & 7) ^ rloc;
    const int cV = 2 * (w * 32 + g * 8 + rloc) + (sraw >> 2);
    pV[g] = Vz + (size_t)cV * 4096 + jb0 + (sraw & 3) * 8;
  }

  auto stage = [&](int d, int t) {
    unsigned char* Kd = lds + d * 16384 + w * 4096;
    unsigned char* Vd = lds + 32768 + d * 16384 + w * 4096;
    #pragma unroll
    for (int g = 0; g < 4; ++g) gload16(pK[g] + (size_t)t * 8192, Kd + g * 1024);
    #pragma unroll
    for (int g = 0; g < 4; ++g) gload16(pV[g] + (size_t)t * 32, Vd + g * 1024);
  };

  f32x4 o0[16] = {}, o1[16] = {};
  float l0 = 0.f, l1 = 0.f;   // per-lane partials; cross-lane reduce at epilogue

  stage(0, 0);
  for (int t = 0; t < 32; ++t) {
    asm volatile("s_waitcnt vmcnt(0)" ::: "memory");
    __builtin_amdgcn_s_barrier();
    __builtin_amdgcn_sched_barrier(0);
    const int cur = t & 1;
    if (t + 1 < 32) stage(cur ^ 1, t + 1);

    const unsigned char* Kb = lds + cur * 16384;
    const unsigned char* Vb = lds + 32768 + cur * 16384;

    // ---- QK^T (swapped): sA[jf][qh] rows j=16jf+4hig+e, col q=l15 ----
    f32x4 sA[2][2] = {};
    __builtin_amdgcn_s_setprio(1);
    #pragma unroll
    for (int ks = 0; ks < 8; ++ks) {
      #pragma unroll
      for (int jf = 0; jf < 2; ++jf) {
        const int jl = jf * 16 + l15;
        bf16x8 kf = *reinterpret_cast<const bf16x8*>(
            Kb + jl * 512 + (((4 * ks + hig) ^ (jl & 7)) << 4));
        sA[jf][0] = __builtin_amdgcn_mfma_f32_16x16x32_bf16(kf, qfr[0][ks], sA[jf][0], 0, 0, 0);
        sA[jf][1] = __builtin_amdgcn_mfma_f32_16x16x32_bf16(kf, qfr[1][ks], sA[jf][1], 0, 0, 0);
      }
    }
    __builtin_amdgcn_s_setprio(0);

    // ---- static-max softmax: P = 2^s (scores O(1) by construction) ----
    #pragma unroll
    for (int jf = 0; jf < 2; ++jf) {
      const int so = (((2 * jf + (hig >> 1)) ^ (l15 & 7)) << 4) + ((hig & 1) << 3);
      {
        float p0 = ex2(sA[jf][0][0]), p1 = ex2(sA[jf][0][1]);
        float p2 = ex2(sA[jf][0][2]), p3 = ex2(sA[jf][0][3]);
        l0 += (p0 + p1) + (p2 + p3);
        union { __bf16 b[4]; uint2 u; } pk;
        pk.b[0] = (__bf16)p0; pk.b[1] = (__bf16)p1;
        pk.b[2] = (__bf16)p2; pk.b[3] = (__bf16)p3;
        *reinterpret_cast<uint2*>(Pw + l15 * 128 + so) = pk.u;
      }
      {
        float p0 = ex2(sA[jf][1][0]), p1 = ex2(sA[jf][1][1]);
        float p2 = ex2(sA[jf][1][2]), p3 = ex2(sA[jf][1][3]);
        l1 += (p0 + p1) + (p2 + p3);
        union { __bf16 b[4]; uint2 u; } pk;
        pk.b[0] = (__bf16)p0; pk.b[1] = (__bf16)p1;
        pk.b[2] = (__bf16)p2; pk.b[3] = (__bf16)p3;
        *reinterpret_cast<uint2*>(Pw + (16 + l15) * 128 + so) = pk.u;
      }
    }

    // ---- PV: A = P rows i, B = V cols c, k = 32 j ----
    const int pso = (hig ^ (l15 & 7)) << 4;
    bf16x8 pa0 = *reinterpret_cast<const bf16x8*>(Pw + l15 * 128 + pso);
    bf16x8 pa1 = *reinterpret_cast<const bf16x8*>(Pw + (16 + l15) * 128 + pso);
    const int vslot = ((l15 & 1) * 4 + hig) ^ (l15 >> 1);
    __builtin_amdgcn_s_setprio(1);
    #pragma unroll
    for (int nf = 0; nf < 16; ++nf) {
      bf16x8 vb = *reinterpret_cast<const bf16x8*>(
          Vb + (8 * nf + (l15 >> 1)) * 128 + (vslot << 4));
      o0[nf] = __builtin_amdgcn_mfma_f32_16x16x32_bf16(pa0, vb, o0[nf], 0, 0, 0);
      o1[nf] = __builtin_amdgcn_mfma_f32_16x16x32_bf16(pa1, vb, o1[nf], 0, 0, 0);
    }
    __builtin_amdgcn_s_setprio(0);
  }

  // deferred cross-lane l reduction (hig-groups hold disjoint j partials)
  l0 += __shfl_xor(l0, 16); l0 += __shfl_xor(l0, 32);
  l1 += __shfl_xor(l1, 16); l1 += __shfl_xor(l1, 32);

  // epilogue: un-normalized partials (bf16) + l for the merge kernel
  unsigned short* Ob = Opart + ((size_t)(jh * 4 + z) * 4096 + q0) * 256;
  #pragma unroll
  for (int qf = 0; qf < 2; ++qf)
    #pragma unroll
    for (int nf = 0; nf < 16; ++nf)
      #pragma unroll
      for (int e = 0; e < 4; ++e) {
        const int row = qf * 16 + 4 * hig + e;
        Ob[(size_t)row * 256 + nf * 16 + l15] = f2bf((qf == 0) ? o0[nf][e] : o1[nf][e]);
      }
  if (hig == 0) {
    const size_t mb = (size_t)(jh * 4 + z) * 4096 + q0;
    lpart[mb + l15] = l0;  lpart[mb + 16 + l15] = l1;
  }
}

// ---------------- merge the four j-quarters (plain sum) -> Ht bf16 ----------------
__global__ __launch_bounds__(256)
void flash_merge(const unsigned short* __restrict__ Opart,
                 const float* __restrict__ lpart, unsigned short* __restrict__ Ht) {
  const int t = threadIdx.x;
  const int r = blockIdx.x * 4 + (t >> 6);   // r = z*4096 + n, in [0,16384)
  const int c = (t & 63) * 4;
  const int z = r >> 12, n = r & 4095;
  float lsum = 0.f;
  #pragma unroll
  for (int h = 0; h < 4; ++h) lsum += lpart[(h * 4 + z) * 4096 + n];
  const float inv = 1.f / lsum;
  float acc[4] = {};
  #pragma unroll
  for (int h = 0; h < 4; ++h) {
    ushort4 v = *reinterpret_cast<const ushort4*>(
        Opart + ((size_t)((h * 4 + z) * 4096 + n)) * 256 + c);
    acc[0] += bf2f(v.x); acc[1] += bf2f(v.y);
    acc[2] += bf2f(v.z); acc[3] += bf2f(v.w);
  }
  ushort4 pk;
  pk.x = f2bf(acc[0] * inv); pk.y = f2bf(acc[1] * inv);
  pk.z = f2bf(acc[2] * inv); pk.w = f2bf(acc[3] * inv);
  *reinterpret_cast<ushort4*>(Ht + (size_t)r * 256 + c) = pk;
}

// ---------------- 128x128 MFMA GEMM (O-projection w/ residual) ----------------
__global__ __launch_bounds__(256)
void gemm_out(const unsigned short* __restrict__ A,
              const unsigned short* __restrict__ B, long bStrideZ,
              float* __restrict__ Out, long oStrideZ,
              const float* __restrict__ bias,
              const float* __restrict__ resid, long rStrideZ,
              int M, int N, int K) {
  __shared__ alignas(1024) unsigned char lds[32768];
  const int tid  = threadIdx.x;
  const int lane = tid & 63;
  const int hi   = lane >> 4;
  const int l15  = lane & 15;
  const int wid  = tid >> 6;
  const int wm = wid >> 1, wn = wid & 1;
  const int z  = blockIdx.z;
  const int m0 = blockIdx.y * 128;
  const int n0 = blockIdx.x * 128;
  const unsigned short* Az = A;
  const unsigned short* Bz = B + (size_t)z * bStrideZ;

  const int c0 = wid * 2, c1 = wid * 2 + 1;
  const int rr = lane >> 2;
  const int qs = (lane & 3) ^ ((lane >> 3) & 3);
  const unsigned short* pa0 = Az + (size_t)(m0 + c0 * 16 + rr) * K + qs * 8;
  const unsigned short* pa1 = Az + (size_t)(m0 + c1 * 16 + rr) * K + qs * 8;
  const unsigned short* pb0 = Bz + (size_t)(n0 + c0 * 16 + rr) * K + qs * 8;
  const unsigned short* pb1 = Bz + (size_t)(n0 + c1 * 16 + rr) * K + qs * 8;
  unsigned char* lA0 = lds + c0 * 1024;
  unsigned char* lA1 = lds + c1 * 1024;
  unsigned char* lB0 = lds + 8192 + c0 * 1024;
  unsigned char* lB1 = lds + 8192 + c1 * 1024;

  const int slot = hi ^ ((l15 >> 1) & 3);
  int roffA[4], roffB[4];
  #pragma unroll
  for (int t = 0; t < 4; ++t) {
    roffA[t] = (wm * 64 + t * 16 + l15) * 64 + slot * 16;
    roffB[t] = 8192 + (wn * 64 + t * 16 + l15) * 64 + slot * 16;
  }

  f32x4 acc[4][4] = {};

  const int nk = K >> 5;
  gload16(pa0, lA0); gload16(pa1, lA1);
  gload16(pb0, lB0); gload16(pb1, lB1);
  __syncthreads();

  int cur = 0;
  for (int kt = 0; kt < nk; ++kt) {
    if (kt + 1 < nk) {
      const size_t ko = (size_t)(kt + 1) * 32;
      const int bo = (cur ^ 1) * 16384;
      gload16(pa0 + ko, lA0 + bo); gload16(pa1 + ko, lA1 + bo);
      gload16(pb0 + ko, lB0 + bo); gload16(pb1 + ko, lB1 + bo);
    }
    const unsigned char* base = lds + cur * 16384;
    bf16x8 af[4], bfr[4];
    #pragma unroll
    for (int t = 0; t < 4; ++t) {
      af[t]  = *reinterpret_cast<const bf16x8*>(base + roffA[t]);
      bfr[t] = *reinterpret_cast<const bf16x8*>(base + roffB[t]);
    }
    #pragma unroll
    for (int mt = 0; mt < 4; ++mt)
      #pragma unroll
      for (int nt = 0; nt < 4; ++nt)
        acc[mt][nt] = __builtin_amdgcn_mfma_f32_16x16x32_bf16(af[mt], bfr[nt], acc[mt][nt], 0, 0, 0);
    __syncthreads();
    cur ^= 1;
  }

  const int gmb = m0 + wm * 64;
  const int gnb = n0 + wn * 64;
  float* O = Out + (size_t)z * oStrideZ;
  const float* R = resid + (size_t)z * rStrideZ;
  #pragma unroll
  for (int mt = 0; mt < 4; ++mt) {
    const int gm0 = gmb + mt * 16 + 4 * hi;
    #pragma unroll
    for (int nt = 0; nt < 4; ++nt) {
      const int gn = gnb + nt * 16 + l15;
      #pragma unroll
      for (int e = 0; e < 4; ++e) {
        size_t idx = (size_t)(gm0 + e) * N + gn;
        O[idx] = acc[mt][nt][e] + bias[gm0 + e] + R[idx];
      }
    }
  }
}

__global__ void ws_too_small(float* out, float v) {
  if (threadIdx.x == 0 && blockIdx.x == 0) out[0] = v;
}

extern "C" void kernel_launch(void* const* d_in, const int* in_sizes, int n_in,
                              void* d_out, int out_size, void* d_ws, size_t ws_size,
                              hipStream_t stream) {
  const float* x     = (const float*)d_in[0];
  const float* gamma = (const float*)d_in[1];
  const float* beta  = (const float*)d_in[2];
  const float* Wq    = (const float*)d_in[3];
  const float* bq    = (const float*)d_in[4];
  const float* Wk    = (const float*)d_in[5];
  const float* bk    = (const float*)d_in[6];
  const float* Wv    = (const float*)d_in[7];
  const float* bv    = (const float*)d_in[8];
  const float* Wo    = (const float*)d_in[9];
  const float* bo    = (const float*)d_in[10];
  float* out = (float*)d_out;

  unsigned char* ws = (unsigned char*)d_ws;
  unsigned short* WB    = (unsigned short*)(ws);             // [4][256][256] bf16 (q,k,v,o)
  unsigned short* hnT   = (unsigned short*)(ws + 524288);    // [4][4096][256]
  float*          lpart = (float*)(ws + 524288);             // [4][4][4096] (reuses hnT after projections)
  unsigned short* Qt    = (unsigned short*)(ws + 8912896);   // [4][4096][256]
  unsigned short* Kt    = (unsigned short*)(ws + 17301504);  // [4][4096][256]
  unsigned short* V     = (unsigned short*)(ws + 25690112);  // [4][256][4096]
  unsigned short* Ht    = (unsigned short*)(ws + 34078720);  // [4][4096][256]
  unsigned short* Opart = (unsigned short*)(ws + 42467328);  // [16][4096][256] bf16

  if (ws_size < 76283904) {
    hipMemsetAsync(d_out, 0, (size_t)out_size * 4, stream);
    ws_too_small<<<1, 64, 0, stream>>>(out, (float)ws_size);
    return;
  }

  prep_weights<<<1024, 256, 0, stream>>>(Wq, Wk, Wv, Wo, WB);
  groupnorm_split<<<256, 512, 0, stream>>>(x, gamma, beta, hnT);

  // fused QKV projections (Q pre-scaled by 1/16*log2e)
  qkv_fused<<<dim3(128, 4), 256, 0, stream>>>(WB, hnT, bq, bk, bv, Qt, Kt, V);

  // fused attention (static-max base-2 softmax), j split 4-way, XCD-swizzled
  flash_attn<<<512, 256, 0, stream>>>(Qt, Kt, V, Opart, lpart);
  flash_merge<<<4096, 256, 0, stream>>>(Opart, lpart, Ht);

  // out[co][n] = sum_c Wo[co][c] * Ht[n][c] + bo[co] + x
  gemm_out<<<dim3(32, 2, 4), 256, 0, stream>>>(
      WB + 196608, Ht, 1048576, out, 1048576, bo, x, 1048576, 256, 4096, 256);
}

// Round 16
// 135.757 us; speedup vs baseline: 1.2517x; 1.0096x over previous
//
#include <hip/hip_runtime.h>

typedef __attribute__((ext_vector_type(4))) float f32x4;
typedef __attribute__((ext_vector_type(8))) __bf16 bf16x8;

__device__ __forceinline__ unsigned short f2bf(float f) {
  unsigned int u = __float_as_uint(f);
  u += 0x7FFFu + ((u >> 16) & 1u);
  return (unsigned short)(u >> 16);
}
__device__ __forceinline__ float bf2f(unsigned short u) {
  return __uint_as_float(((unsigned int)u) << 16);
}
__device__ __forceinline__ float ex2(float x) {
  return __builtin_amdgcn_exp2f(x);   // native v_exp_f32 (base-2)
}

__device__ __forceinline__ void gload16(const void* g, void* l) {
  __builtin_amdgcn_global_load_lds(
      (const __attribute__((address_space(1))) void*)g,
      (__attribute__((address_space(3))) void*)l, 16, 0, 0);
}

#define QSCALE 0.09016844005555897f  /* (1/16) * log2(e) */

// ---------------- weight fp32 -> bf16 ----------------
__global__ __launch_bounds__(256)
void prep_weights(const float* __restrict__ wq, const float* __restrict__ wk,
                  const float* __restrict__ wv, const float* __restrict__ wo,
                  unsigned short* __restrict__ out) {
  int i = blockIdx.x * 256 + threadIdx.x;  // 4 * 65536 total
  const float* src = (i < 65536) ? wq : (i < 131072) ? wk : (i < 196608) ? wv : wo;
  out[i] = f2bf(src[i & 65535]);
}

// ---------------- GroupNorm, split-stats version ----------------
__global__ __launch_bounds__(512)
void groupnorm_split(const float* __restrict__ x, const float* __restrict__ gamma,
                     const float* __restrict__ beta, unsigned short* __restrict__ hnT) {
  const int blk = blockIdx.x;
  const int h = blk & 1, bg = blk >> 1;
  const int b = bg >> 5, g = bg & 31;
  const int tid = threadIdx.x;
  const float* xg = x + ((size_t)b * 256 + (size_t)g * 8) * 4096;
  const float* xo = xg + h * 2048;          // own half
  const float* xr = xg + (h ^ 1) * 2048;    // other half (stats only)

  float v[8][4];
  float s = 0.f, ss = 0.f;
  #pragma unroll
  for (int c = 0; c < 8; ++c)
    #pragma unroll
    for (int s2 = 0; s2 < 4; ++s2) {
      float val = xo[c * 4096 + s2 * 512 + tid];
      v[c][s2] = val; s += val; ss += val * val;
    }
  #pragma unroll
  for (int c = 0; c < 8; ++c)
    #pragma unroll
    for (int s2 = 0; s2 < 4; ++s2) {
      float val = xr[c * 4096 + s2 * 512 + tid];
      s += val; ss += val * val;
    }
  __shared__ float rs[8], rss[8];
  for (int m = 1; m <= 32; m <<= 1) { s += __shfl_xor(s, m); ss += __shfl_xor(ss, m); }
  const int lane = tid & 63, wid = tid >> 6;
  if (lane == 0) { rs[wid] = s; rss[wid] = ss; }
  __syncthreads();
  s = 0.f; ss = 0.f;
  #pragma unroll
  for (int i = 0; i < 8; ++i) { s += rs[i]; ss += rss[i]; }
  const float mean = s * (1.f / 32768.f);
  const float var  = ss * (1.f / 32768.f) - mean * mean;
  const float rstd = rsqrtf(var + 1e-6f);

  float gk[8], bk2[8];
  #pragma unroll
  for (int c = 0; c < 8; ++c) {
    float ga = gamma[g * 8 + c] * rstd;
    gk[c]  = ga;
    bk2[c] = beta[g * 8 + c] - mean * ga;
  }
  unsigned short* outp = hnT + (size_t)b * 4096 * 256 + g * 8;
  #pragma unroll
  for (int s2 = 0; s2 < 4; ++s2) {
    const int n = h * 2048 + s2 * 512 + tid;
    union { unsigned short u[8]; uint4 q; } pk;
    #pragma unroll
    for (int c = 0; c < 8; ++c) pk.u[c] = f2bf(v[c][s2] * gk[c] + bk2[c]);
    *reinterpret_cast<uint4*>(outp + (size_t)n * 256) = pk.q;
  }
}

// ---------------- fused QKV projection ----------------
__global__ __launch_bounds__(256, 2)
void qkv_fused(const unsigned short* __restrict__ WB,
               const unsigned short* __restrict__ hnT,
               const float* __restrict__ bq, const float* __restrict__ bk,
               const float* __restrict__ bv,
               unsigned short* __restrict__ Qt, unsigned short* __restrict__ Kt,
               unsigned short* __restrict__ Vp) {
  __shared__ alignas(1024) unsigned char lds[32768];  // B 16KB @0, A dbuf 2x8KB @16384
  const int tid = threadIdx.x, lane = tid & 63, w = tid >> 6;
  const int hig = lane >> 4, l15 = lane & 15;
  const int z = blockIdx.y, nt = blockIdx.x;
  const int n0 = nt * 32;
  const size_t zoff = (size_t)z * 1048576;
  const unsigned short* hnB = hnT + zoff + (size_t)n0 * 256;

  // stage B tile (32 rows x 512B): 4 passes x 256 lanes x 16B
  #pragma unroll
  for (int p = 0; p < 4; ++p) {
    const int idx = p * 256 + tid;
    const int r = idx >> 5, sl = idx & 31;
    gload16(hnB + (size_t)r * 256 + ((sl ^ (r & 7)) << 3), lds + idx * 16);
  }

  const int qs = (lane & 3) ^ ((lane >> 3) & 3);
  const int ar = tid >> 2, asq = tid & 3;
  auto stageA = [&](int d, int s) {
    const unsigned short* base = WB + (s >> 3) * 32768 + (s & 7) * 32 + qs * 8;
    unsigned char* dst = lds + 16384 + d * 8192;
    gload16(base + (size_t)ar * 256,        dst + ar * 64 + asq * 16);
    gload16(base + (size_t)(ar + 64) * 256, dst + (ar + 64) * 64 + asq * 16);
  };

  const int aslot = hig ^ ((l15 >> 1) & 3);
  f32x4 acc[2][2] = {};

  stageA(0, 0);
  __syncthreads();  // drains B + A(0)

  for (int s = 0; s < 48; ++s) {
    const int d = s & 1;
    if (s + 1 < 48) stageA(d ^ 1, s + 1);
    const int kt = s & 7;
    bf16x8 af[2];
    #pragma unroll
    for (int mf = 0; mf < 2; ++mf)
      af[mf] = *reinterpret_cast<const bf16x8*>(
          lds + 16384 + d * 8192 + (w * 32 + mf * 16 + l15) * 64 + aslot * 16);
    #pragma unroll
    for (int nf = 0; nf < 2; ++nf) {
      const int rb = nf * 16 + l15;
      bf16x8 bfr = *reinterpret_cast<const bf16x8*>(
          lds + rb * 512 + (((kt * 4 + hig) ^ (rb & 7)) << 4));
      acc[0][nf] = __builtin_amdgcn_mfma_f32_16x16x32_bf16(af[0], bfr, acc[0][nf], 0, 0, 0);
      acc[1][nf] = __builtin_amdgcn_mfma_f32_16x16x32_bf16(af[1], bfr, acc[1][nf], 0, 0, 0);
    }
    if (kt == 7) {  // epilogue for tile sel
      const int sel = s >> 3, wsel = sel >> 1, mh = sel & 1;
      #pragma unroll
      for (int mf = 0; mf < 2; ++mf) {
        const int gm0 = mh * 128 + w * 32 + mf * 16 + 4 * hig;
        #pragma unroll
        for (int nf = 0; nf < 2; ++nf) {
          const int n = n0 + nf * 16 + l15;
          if (wsel == 0) {
            ushort4 pk;
            pk.x = f2bf((acc[mf][nf][0] + bq[gm0])     * QSCALE);
            pk.y = f2bf((acc[mf][nf][1] + bq[gm0 + 1]) * QSCALE);
            pk.z = f2bf((acc[mf][nf][2] + bq[gm0 + 2]) * QSCALE);
            pk.w = f2bf((acc[mf][nf][3] + bq[gm0 + 3]) * QSCALE);
            *reinterpret_cast<ushort4*>(Qt + zoff + (size_t)n * 256 + gm0) = pk;
          } else if (wsel == 1) {
            ushort4 pk;
            pk.x = f2bf(acc[mf][nf][0] + bk[gm0]);
            pk.y = f2bf(acc[mf][nf][1] + bk[gm0 + 1]);
            pk.z = f2bf(acc[mf][nf][2] + bk[gm0 + 2]);
            pk.w = f2bf(acc[mf][nf][3] + bk[gm0 + 3]);
            *reinterpret_cast<ushort4*>(Kt + zoff + (size_t)n * 256 + gm0) = pk;
          } else {
            #pragma unroll
            for (int e = 0; e < 4; ++e)
              Vp[zoff + (size_t)(gm0 + e) * 4096 + n] = f2bf(acc[mf][nf][e] + bv[gm0 + e]);
          }
          acc[mf][nf] = f32x4{0.f, 0.f, 0.f, 0.f};
        }
      }
    }
    __syncthreads();
  }
}

// ---------------- fused flash attention (r13/r15, unchanged) ----------------
__global__ __launch_bounds__(256, 2)
void flash_attn(const unsigned short* __restrict__ Qt,
                const unsigned short* __restrict__ Kt,
                const unsigned short* __restrict__ Vp,
                unsigned short* __restrict__ Opart, float* __restrict__ lpart) {
  __shared__ alignas(1024) unsigned char lds[81920];
  const int tid = threadIdx.x, lane = tid & 63, w = tid >> 6;
  const int hig = lane >> 4, l15 = lane & 15;
  // XCD-aware bijective decode (hardware XCD = blockIdx % 8)
  const int bid = blockIdx.x;
  const int xcd = bid & 7, k = bid >> 3;
  const int combo = xcd * 2 + (k >> 5);       // 0..15
  const int jh = combo & 3, z = combo >> 2, qtb = k & 31;
  const size_t zoff = (size_t)z * 1048576;
  const unsigned short* Qz = Qt + zoff;
  const unsigned short* Kz = Kt + zoff;
  const unsigned short* Vz = Vp + zoff;
  const int q0 = qtb * 128 + w * 32;
  const int jb0 = jh * 1024;

  bf16x8 qfr[2][8];
  #pragma unroll
  for (int qf = 0; qf < 2; ++qf)
    #pragma unroll
    for (int ks = 0; ks < 8; ++ks)
      qfr[qf][ks] = *reinterpret_cast<const bf16x8*>(
          Qz + (size_t)(q0 + qf * 16 + l15) * 256 + ks * 32 + hig * 8);

  unsigned char* Pw = lds + 65536 + w * 4096;

  const unsigned short* pK[4];
  const unsigned short* pV[4];
  #pragma unroll
  for (int g = 0; g < 4; ++g) {
    const int jr = w * 8 + g * 2 + (lane >> 5);
    pK[g] = Kz + (size_t)(jb0 + jr) * 256 + (((lane & 31) ^ (jr & 7)) << 3);
    // V: row-pair r=c>>1 (128B), raw slot = 4(c&1)+(j>>3), stored ^ (r&7).
    const int rloc = lane >> 3;
    const int sraw = (lane & 7) ^ rloc;
    const int cV = 2 * (w * 32 + g * 8 + rloc) + (sraw >> 2);
    pV[g] = Vz + (size_t)cV * 4096 + jb0 + (sraw & 3) * 8;
  }

  auto stage = [&](int d, int t) {
    unsigned char* Kd = lds + d * 16384 + w * 4096;
    unsigned char* Vd = lds + 32768 + d * 16384 + w * 4096;
    #pragma unroll
    for (int g = 0; g < 4; ++g) gload16(pK[g] + (size_t)t * 8192, Kd + g * 1024);
    #pragma unroll
    for (int g = 0; g < 4; ++g) gload16(pV[g] + (size_t)t * 32, Vd + g * 1024);
  };

  f32x4 o0[16] = {}, o1[16] = {};
  float l0 = 0.f, l1 = 0.f;   // per-lane partials; cross-lane reduce at epilogue

  stage(0, 0);
  for (int t = 0; t < 32; ++t) {
    asm volatile("s_waitcnt vmcnt(0)" ::: "memory");
    __builtin_amdgcn_s_barrier();
    __builtin_amdgcn_sched_barrier(0);
    const int cur = t & 1;
    if (t + 1 < 32) stage(cur ^ 1, t + 1);

    const unsigned char* Kb = lds + cur * 16384;
    const unsigned char* Vb = lds + 32768 + cur * 16384;

    // ---- QK^T (swapped): sA[jf][qh] rows j=16jf+4hig+e, col q=l15 ----
    f32x4 sA[2][2] = {};
    __builtin_amdgcn_s_setprio(1);
    #pragma unroll
    for (int ks = 0; ks < 8; ++ks) {
      #pragma unroll
      for (int jf = 0; jf < 2; ++jf) {
        const int jl = jf * 16 + l15;
        bf16x8 kf = *reinterpret_cast<const bf16x8*>(
            Kb + jl * 512 + (((4 * ks + hig) ^ (jl & 7)) << 4));
        sA[jf][0] = __builtin_amdgcn_mfma_f32_16x16x32_bf16(kf, qfr[0][ks], sA[jf][0], 0, 0, 0);
        sA[jf][1] = __builtin_amdgcn_mfma_f32_16x16x32_bf16(kf, qfr[1][ks], sA[jf][1], 0, 0, 0);
      }
    }
    __builtin_amdgcn_s_setprio(0);

    // ---- static-max softmax: P = 2^s (scores O(1) by construction) ----
    #pragma unroll
    for (int jf = 0; jf < 2; ++jf) {
      const int so = (((2 * jf + (hig >> 1)) ^ (l15 & 7)) << 4) + ((hig & 1) << 3);
      {
        float p0 = ex2(sA[jf][0][0]), p1 = ex2(sA[jf][0][1]);
        float p2 = ex2(sA[jf][0][2]), p3 = ex2(sA[jf][0][3]);
        l0 += (p0 + p1) + (p2 + p3);
        union { __bf16 b[4]; uint2 u; } pk;
        pk.b[0] = (__bf16)p0; pk.b[1] = (__bf16)p1;
        pk.b[2] = (__bf16)p2; pk.b[3] = (__bf16)p3;
        *reinterpret_cast<uint2*>(Pw + l15 * 128 + so) = pk.u;
      }
      {
        float p0 = ex2(sA[jf][1][0]), p1 = ex2(sA[jf][1][1]);
        float p2 = ex2(sA[jf][1][2]), p3 = ex2(sA[jf][1][3]);
        l1 += (p0 + p1) + (p2 + p3);
        union { __bf16 b[4]; uint2 u; } pk;
        pk.b[0] = (__bf16)p0; pk.b[1] = (__bf16)p1;
        pk.b[2] = (__bf16)p2; pk.b[3] = (__bf16)p3;
        *reinterpret_cast<uint2*>(Pw + (16 + l15) * 128 + so) = pk.u;
      }
    }

    // ---- PV: A = P rows i, B = V cols c, k = 32 j ----
    const int pso = (hig ^ (l15 & 7)) << 4;
    bf16x8 pa0 = *reinterpret_cast<const bf16x8*>(Pw + l15 * 128 + pso);
    bf16x8 pa1 = *reinterpret_cast<const bf16x8*>(Pw + (16 + l15) * 128 + pso);
    const int vslot = ((l15 & 1) * 4 + hig) ^ (l15 >> 1);
    __builtin_amdgcn_s_setprio(1);
    #pragma unroll
    for (int nf = 0; nf < 16; ++nf) {
      bf16x8 vb = *reinterpret_cast<const bf16x8*>(
          Vb + (8 * nf + (l15 >> 1)) * 128 + (vslot << 4));
      o0[nf] = __builtin_amdgcn_mfma_f32_16x16x32_bf16(pa0, vb, o0[nf], 0, 0, 0);
      o1[nf] = __builtin_amdgcn_mfma_f32_16x16x32_bf16(pa1, vb, o1[nf], 0, 0, 0);
    }
    __builtin_amdgcn_s_setprio(0);
  }

  // deferred cross-lane l reduction (hig-groups hold disjoint j partials)
  l0 += __shfl_xor(l0, 16); l0 += __shfl_xor(l0, 32);
  l1 += __shfl_xor(l1, 16); l1 += __shfl_xor(l1, 32);

  // epilogue: un-normalized partials (bf16) + l for gemm_out
  unsigned short* Ob = Opart + ((size_t)(jh * 4 + z) * 4096 + q0) * 256;
  #pragma unroll
  for (int qf = 0; qf < 2; ++qf)
    #pragma unroll
    for (int nf = 0; nf < 16; ++nf)
      #pragma unroll
      for (int e = 0; e < 4; ++e) {
        const int row = qf * 16 + 4 * hig + e;
        Ob[(size_t)row * 256 + nf * 16 + l15] = f2bf((qf == 0) ? o0[nf][e] : o1[nf][e]);
      }
  if (hig == 0) {
    const size_t mb = (size_t)(jh * 4 + z) * 4096 + q0;
    lpart[mb + l15] = l0;  lpart[mb + 16 + l15] = l1;
  }
}

// ---------------- O-projection GEMM fused with the 4-way partial merge ----------------
// B operand = Sum_jh Opart[jh][z][n][c] (reg-staged sum, ds_write to the same
// swizzled slots the gload16 path used); 1/Sum_jh l folded into the epilogue:
// out[co][n] = (Wo . Hsum)[co][n] * invl[n] + bo[co] + x[co][n].
__global__ __launch_bounds__(256)
void gemm_out(const unsigned short* __restrict__ A,
              const unsigned short* __restrict__ Opart,
              const float* __restrict__ lpart,
              float* __restrict__ Out, long oStrideZ,
              const float* __restrict__ bias,
              const float* __restrict__ resid, long rStrideZ,
              int M, int N, int K) {
  __shared__ alignas(1024) unsigned char lds[32768];
  const int tid  = threadIdx.x;
  const int lane = tid & 63;
  const int hi   = lane >> 4;
  const int l15  = lane & 15;
  const int wid  = tid >> 6;
  const int wm = wid >> 1, wn = wid & 1;
  const int z  = blockIdx.z;
  const int m0 = blockIdx.y * 128;
  const int n0 = blockIdx.x * 128;
  const size_t CH = 4194304;  // Opart jh-chunk stride (ushorts)

  const int c0 = wid * 2, c1 = wid * 2 + 1;
  const int rr = lane >> 2;
  const int qs = (lane & 3) ^ ((lane >> 3) & 3);
  const unsigned short* pa0 = A + (size_t)(m0 + c0 * 16 + rr) * K + qs * 8;
  const unsigned short* pa1 = A + (size_t)(m0 + c1 * 16 + rr) * K + qs * 8;
  const unsigned short* pb0 = Opart + (size_t)(z * 4096 + n0 + c0 * 16 + rr) * 256 + qs * 8;
  const unsigned short* pb1 = Opart + (size_t)(z * 4096 + n0 + c1 * 16 + rr) * 256 + qs * 8;
  unsigned char* lA0 = lds + c0 * 1024;
  unsigned char* lA1 = lds + c1 * 1024;

  auto sum4 = [&](const unsigned short* p) -> uint4 {
    union U { uint4 v; unsigned short u[8]; } a, b, c, d, r;
    a.v = *reinterpret_cast<const uint4*>(p);
    b.v = *reinterpret_cast<const uint4*>(p + CH);
    c.v = *reinterpret_cast<const uint4*>(p + 2 * CH);
    d.v = *reinterpret_cast<const uint4*>(p + 3 * CH);
    #pragma unroll
    for (int i = 0; i < 8; ++i)
      r.u[i] = f2bf((bf2f(a.u[i]) + bf2f(b.u[i])) + (bf2f(c.u[i]) + bf2f(d.u[i])));
    return r.v;
  };

  const int slot = hi ^ ((l15 >> 1) & 3);
  int roffA[4], roffB[4];
  #pragma unroll
  for (int t = 0; t < 4; ++t) {
    roffA[t] = (wm * 64 + t * 16 + l15) * 64 + slot * 16;
    roffB[t] = 8192 + (wn * 64 + t * 16 + l15) * 64 + slot * 16;
  }

  f32x4 acc[4][4] = {};

  const int nk = K >> 5;
  // prologue: stage tile 0
  gload16(pa0, lA0); gload16(pa1, lA1);
  *reinterpret_cast<uint4*>(lds + 8192 + c0 * 1024 + lane * 16) = sum4(pb0);
  *reinterpret_cast<uint4*>(lds + 8192 + c1 * 1024 + lane * 16) = sum4(pb1);
  __syncthreads();

  int cur = 0;
  for (int kt = 0; kt < nk; ++kt) {
    const int bo = (cur ^ 1) * 16384;
    uint4 sb0, sb1;
    if (kt + 1 < nk) {
      const size_t ko = (size_t)(kt + 1) * 32;
      gload16(pa0 + ko, lA0 + bo); gload16(pa1 + ko, lA1 + bo);
      sb0 = sum4(pb0 + ko);   // loads issue here, overlap MFMA below
      sb1 = sum4(pb1 + ko);
    }
    const unsigned char* base = lds + cur * 16384;
    bf16x8 af[4], bfr[4];
    #pragma unroll
    for (int t = 0; t < 4; ++t) {
      af[t]  = *reinterpret_cast<const bf16x8*>(base + roffA[t]);
      bfr[t] = *reinterpret_cast<const bf16x8*>(base + roffB[t]);
    }
    #pragma unroll
    for (int mt = 0; mt < 4; ++mt)
      #pragma unroll
      for (int nt = 0; nt < 4; ++nt)
        acc[mt][nt] = __builtin_amdgcn_mfma_f32_16x16x32_bf16(af[mt], bfr[nt], acc[mt][nt], 0, 0, 0);
    if (kt + 1 < nk) {
      *reinterpret_cast<uint4*>(lds + bo + 8192 + c0 * 1024 + lane * 16) = sb0;
      *reinterpret_cast<uint4*>(lds + bo + 8192 + c1 * 1024 + lane * 16) = sb1;
    }
    __syncthreads();
    cur ^= 1;
  }

  const int gmb = m0 + wm * 64;
  const int gnb = n0 + wn * 64;
  float* O = Out + (size_t)z * oStrideZ;
  const float* R = resid + (size_t)z * rStrideZ;
  float invl[4];
  #pragma unroll
  for (int nt = 0; nt < 4; ++nt) {
    const int gn = gnb + nt * 16 + l15;
    float ls = (lpart[(size_t)z * 4096 + gn]            + lpart[(size_t)(4 + z) * 4096 + gn]) +
               (lpart[(size_t)(8 + z) * 4096 + gn]      + lpart[(size_t)(12 + z) * 4096 + gn]);
    invl[nt] = 1.f / ls;
  }
  #pragma unroll
  for (int mt = 0; mt < 4; ++mt) {
    const int gm0 = gmb + mt * 16 + 4 * hi;
    #pragma unroll
    for (int nt = 0; nt < 4; ++nt) {
      const int gn = gnb + nt * 16 + l15;
      #pragma unroll
      for (int e = 0; e < 4; ++e) {
        size_t idx = (size_t)(gm0 + e) * N + gn;
        O[idx] = acc[mt][nt][e] * invl[nt] + bias[gm0 + e] + R[idx];
      }
    }
  }
}

__global__ void ws_too_small(float* out, float v) {
  if (threadIdx.x == 0 && blockIdx.x == 0) out[0] = v;
}

extern "C" void kernel_launch(void* const* d_in, const int* in_sizes, int n_in,
                              void* d_out, int out_size, void* d_ws, size_t ws_size,
                              hipStream_t stream) {
  const float* x     = (const float*)d_in[0];
  const float* gamma = (const float*)d_in[1];
  const float* beta  = (const float*)d_in[2];
  const float* Wq    = (const float*)d_in[3];
  const float* bq    = (const float*)d_in[4];
  const float* Wk    = (const float*)d_in[5];
  const float* bk    = (const float*)d_in[6];
  const float* Wv    = (const float*)d_in[7];
  const float* bv    = (const float*)d_in[8];
  const float* Wo    = (const float*)d_in[9];
  const float* bo    = (const float*)d_in[10];
  float* out = (float*)d_out;

  unsigned char* ws = (unsigned char*)d_ws;
  unsigned short* WB    = (unsigned short*)(ws);             // [4][256][256] bf16 (q,k,v,o)
  unsigned short* hnT   = (unsigned short*)(ws + 524288);    // [4][4096][256]
  float*          lpart = (float*)(ws + 524288);             // [4][4][4096] (reuses hnT after projections)
  unsigned short* Qt    = (unsigned short*)(ws + 8912896);   // [4][4096][256]
  unsigned short* Kt    = (unsigned short*)(ws + 17301504);  // [4][4096][256]
  unsigned short* V     = (unsigned short*)(ws + 25690112);  // [4][256][4096]
  unsigned short* Opart = (unsigned short*)(ws + 42467328);  // [16][4096][256] bf16

  if (ws_size < 76283904) {
    hipMemsetAsync(d_out, 0, (size_t)out_size * 4, stream);
    ws_too_small<<<1, 64, 0, stream>>>(out, (float)ws_size);
    return;
  }

  prep_weights<<<1024, 256, 0, stream>>>(Wq, Wk, Wv, Wo, WB);
  groupnorm_split<<<256, 512, 0, stream>>>(x, gamma, beta, hnT);

  // fused QKV projections (Q pre-scaled by 1/16*log2e)
  qkv_fused<<<dim3(128, 4), 256, 0, stream>>>(WB, hnT, bq, bk, bv, Qt, Kt, V);

  // fused attention (static-max base-2 softmax), j split 4-way, XCD-swizzled
  flash_attn<<<512, 256, 0, stream>>>(Qt, Kt, V, Opart, lpart);

  // out[co][n] = (Wo . Sum_jh Opart)[co][n] / Sum_jh l[n] + bo[co] + x
  gemm_out<<<dim3(32, 2, 4), 256, 0, stream>>>(
      WB + 196608, Opart, lpart, out, 1048576, bo, x, 1048576, 256, 4096, 256);
}